// Round 2
// baseline (5617.565 us; speedup 1.0000x reference)
//
#include <hip/hip_runtime.h>
#include <hip/hip_bf16.h>

#define N_NODES 50000
#define N_EDGES 800000
#define F_NODE  1363
#define F_STRUCT 83
#define F_ESM   1280
#define H1      128
#define H2      64
#define TN      32    // nodes per block (non-edge kernels)

// edge-kernel tiling
#define TEM      64                 // edges per tile
#define NTILES   (N_EDGES / TEM)    // 12500
#define GRID_E   768                // persistent blocks (3 per CU)
#define SIN_LD   264                // 256 + 8 pad: stride 132 dwords == 4 mod 32 -> ~2-way (free)
#define SM_LD    136                // 128 + 8 pad: stride 68 dwords == 4 mod 32 -> ~2-way (free)

// ffnn MFMA tiling
#define TFM      64                 // nodes per ffnn block
#define SA_LD    136                // 128 + 8 shorts
#define SH_LD    264                // 256 + 8 shorts

typedef __attribute__((ext_vector_type(8))) short short8;   // 8 x bf16 (4 VGPRs)
typedef __attribute__((ext_vector_type(4))) float floatx4;  // MFMA accumulator

__device__ __forceinline__ float silu_f(float x) { return x / (1.f + __expf(-x)); }
__device__ __forceinline__ float sigm_f(float x) { return 1.f / (1.f + __expf(-x)); }

// fp32 -> bf16 bits, round-to-nearest-even (finite inputs only)
__device__ __forceinline__ unsigned short f2bf(float f) {
    unsigned int u = __float_as_uint(f);
    unsigned int r = (u + 0x7FFFu + ((u >> 16) & 1u)) >> 16;
    return (unsigned short)r;
}
// packed bf16x2 -> floats
__device__ __forceinline__ float bflo(unsigned int u) { return __uint_as_float(u << 16); }
__device__ __forceinline__ float bfhi(unsigned int u) { return __uint_as_float(u & 0xFFFF0000u); }

// ---------------------------------------------------------------- zero-fill
__global__ void k_zero(float4* __restrict__ p, int n4) {
    int i = blockIdx.x * 256 + threadIdx.x;
    if (i < n4) p[i] = make_float4(0.f, 0.f, 0.f, 0.f);
}

// ---------------------------------------------------------------- h = h0 @ emb_w + emb_b
__global__ __launch_bounds__(H1) void k_emb(const float* __restrict__ na,
                                            const float* __restrict__ w,
                                            const float* __restrict__ b,
                                            float* __restrict__ h) {
    __shared__ float s0[F_STRUCT];
    int n = blockIdx.x, tid = threadIdx.x;
    if (tid < F_STRUCT) s0[tid] = na[n * F_NODE + tid];
    __syncthreads();
    float acc = b[tid];
    for (int k = 0; k < F_STRUCT; ++k)
        acc = fmaf(s0[k], w[k * H1 + tid], acc);
    h[n * H1 + tid] = acc;
}

// ---------------------------------------------------------------- pack fp32 [K x N] -> bf16 B-fragment order
// dst[(k/8)*N + n] is a short8 holding w[k/8*8 + j][n], j=0..7  (one 16B load per MFMA B-frag)
__global__ __launch_bounds__(256) void k_cvt_pack(const float* __restrict__ src,
                                                  unsigned short* __restrict__ dst,
                                                  int total, int logn) {
    int gid = blockIdx.x * 256 + threadIdx.x;
    if (gid >= total) return;
    int n   = 1 << logn;
    int kb  = gid >> logn;
    int col = gid & (n - 1);
    short8 v;
    #pragma unroll
    for (int j = 0; j < 8; ++j)
        v[j] = (short)f2bf(src[(kb * 8 + j) * n + col]);
    *(short8*)&dst[(size_t)gid * 8] = v;
}

// ---------------------------------------------------------------- edge MLP via MFMA bf16
// Persistent blocks, 3/CU. GEMM1: [64x256]@[256x128] (radial/ea applied as fp32
// rank-2 update); GEMM2: [64x128]@[128x128] with B streamed per-tile from the
// pre-packed bf16 buffer (L2-resident) to keep unified regs under the 3-wave cap.
// mfma_f32_16x16x32_bf16 layouts (verified, learn_hip m89/m91/m120):
//   A[m = lane&15][k = (lane>>4)*8 + j]   (short8, j=0..7)
//   B[k = (lane>>4)*8 + j][n = lane&15]
//   D: col = lane&15, row = (lane>>4)*4 + reg
__global__ __launch_bounds__(256, 3) void k_edge_mfma(
    const float* __restrict__ h, const int* __restrict__ ei,
    const float* __restrict__ coords, const float* __restrict__ ea,
    const float* __restrict__ ew1, const float* __restrict__ eb1,
    const unsigned short* __restrict__ wb2, const float* __restrict__ eb2,
    const float* __restrict__ aw,  const float* __restrict__ ab,
    float* __restrict__ agg) {

    __shared__ unsigned short sIn[TEM * SIN_LD];   // 33792 B
    __shared__ unsigned short sM [TEM * SM_LD];    // 17408 B
    __shared__ float s_aw[H1];
    __shared__ float s_p[4][TEM];
    __shared__ float s_att[TEM];
    __shared__ float s_rad[TEM], s_ea[TEM];
    __shared__ int   s_r[TEM], s_c[TEM];

    const int tid  = threadIdx.x;
    const int wv   = tid >> 6;
    const int lane = tid & 63;
    const int l16  = lane & 15;
    const int quad = lane >> 4;

    if (tid < H1) s_aw[tid] = aw[tid];

    // ---- load GEMM1 B-fragments (weights) once per block into registers (K=256)
    short8 B1[2][8];
    float  bias1[2], bias2[2], w1r[2], w1e[2];
    #pragma unroll
    for (int s = 0; s < 2; ++s) {
        const int n = (2 * wv + s) * 16 + l16;
        bias1[s] = eb1[n];
        bias2[s] = eb2[n];
        w1r[s]   = ew1[256 * H1 + n];   // radial weight row
        w1e[s]   = ew1[257 * H1 + n];   // edge-attr weight row
        #pragma unroll
        for (int kt = 0; kt < 8; ++kt) {
            short8 f;
            #pragma unroll
            for (int j = 0; j < 8; ++j) {
                int k = kt * 32 + quad * 8 + j;
                f[j] = (short)f2bf(ew1[k * H1 + n]);
            }
            B1[s][kt] = f;
        }
    }
    const float ab0 = ab[0];

    for (int t = blockIdx.x; t < NTILES; t += GRID_E) {
        const int e0 = t * TEM;
        __syncthreads();   // previous iteration fully done with shared state

        if (tid < TEM) {
            int r = ei[e0 + tid], c = ei[N_EDGES + e0 + tid];
            s_r[tid] = r; s_c[tid] = c;
            float dx = coords[r*3+0] - coords[c*3+0];
            float dy = coords[r*3+1] - coords[c*3+1];
            float dz = coords[r*3+2] - coords[c*3+2];
            s_rad[tid] = dx*dx + dy*dy + dz*dz;
            s_ea[tid]  = ea[e0 + tid];
        }
        __syncthreads();

        // gather: edge_in[e][0:128]=h[row], [128:256]=h[col], fp32 -> bf16
        #pragma unroll
        for (int i = 0; i < 16; ++i) {
            int idx  = i * 256 + tid;
            int e    = idx >> 6;
            int part = idx & 63;
            const float* src = (part < 32)
                ? (h + (size_t)s_r[e] * H1 + part * 4)
                : (h + (size_t)s_c[e] * H1 + (part - 32) * 4);
            float4 x = *(const float4*)src;
            unsigned int lo = (unsigned)f2bf(x.x) | ((unsigned)f2bf(x.y) << 16);
            unsigned int hi = (unsigned)f2bf(x.z) | ((unsigned)f2bf(x.w) << 16);
            *(uint2*)&sIn[e * SIN_LD + part * 4] = make_uint2(lo, hi);
        }
        __syncthreads();

        // ---- GEMM1: acc[mt][s] = edge_in @ ew1 + b1  (K=256 MFMA part)
        floatx4 acc[4][2];
        #pragma unroll
        for (int mt = 0; mt < 4; ++mt)
            #pragma unroll
            for (int s = 0; s < 2; ++s)
                acc[mt][s] = (floatx4){bias1[s], bias1[s], bias1[s], bias1[s]};
        #pragma unroll
        for (int kt = 0; kt < 8; ++kt) {
            short8 A[4];
            #pragma unroll
            for (int mt = 0; mt < 4; ++mt)
                A[mt] = *(const short8*)&sIn[(mt*16 + l16) * SIN_LD + kt*32 + quad*8];
            #pragma unroll
            for (int mt = 0; mt < 4; ++mt)
                #pragma unroll
                for (int s = 0; s < 2; ++s)
                    acc[mt][s] = __builtin_amdgcn_mfma_f32_16x16x32_bf16(
                        A[mt], B1[s][kt], acc[mt][s], 0, 0, 0);
        }
        // rank-2 update: + radial*w1[256][n] + ea*w1[257][n]  (fp32, exact placement)
        #pragma unroll
        for (int mt = 0; mt < 4; ++mt)
            #pragma unroll
            for (int r = 0; r < 4; ++r) {
                int edge = mt*16 + quad*4 + r;
                float rad = s_rad[edge], ev = s_ea[edge];
                #pragma unroll
                for (int s = 0; s < 2; ++s)
                    acc[mt][s][r] = fmaf(rad, w1r[s], fmaf(ev, w1e[s], acc[mt][s][r]));
            }

        // stream GEMM2 B-fragments for this tile (L2-resident packed buffer);
        // issued here so the loads overlap the sM write + barrier + att phase
        short8 B2f[2][4];
        #pragma unroll
        for (int kt = 0; kt < 4; ++kt)
            #pragma unroll
            for (int s = 0; s < 2; ++s)
                B2f[s][kt] = *(const short8*)&wb2[((size_t)(kt*4 + quad) * H1 + (2*wv + s)*16 + l16) * 8];

        // silu -> sM (bf16 A-operand of GEMM2)
        #pragma unroll
        for (int mt = 0; mt < 4; ++mt)
            #pragma unroll
            for (int s = 0; s < 2; ++s)
                #pragma unroll
                for (int r = 0; r < 4; ++r) {
                    int row = mt*16 + quad*4 + r;
                    int col = (2*wv + s)*16 + l16;
                    sM[row * SM_LD + col] = f2bf(silu_f(acc[mt][s][r]));
                }
        __syncthreads();

        // attention partials (VALU) — independent of GEMM2 (MFMA), both read sM
        {
            int e = tid & 63, part = tid >> 6;
            const uint2* pm  = (const uint2*)&sM[e * SM_LD + part * 32];
            const float* paw = &s_aw[part * 32];
            float ssum = 0.f;
            #pragma unroll
            for (int j = 0; j < 8; ++j) {
                uint2 u = pm[j];
                ssum = fmaf(bflo(u.x), paw[4*j+0], ssum);
                ssum = fmaf(bfhi(u.x), paw[4*j+1], ssum);
                ssum = fmaf(bflo(u.y), paw[4*j+2], ssum);
                ssum = fmaf(bfhi(u.y), paw[4*j+3], ssum);
            }
            s_p[part][e] = ssum;
        }

        // ---- GEMM2: acc2[mt][s] = m @ ew2 + b2
        floatx4 acc2[4][2];
        #pragma unroll
        for (int mt = 0; mt < 4; ++mt)
            #pragma unroll
            for (int s = 0; s < 2; ++s)
                acc2[mt][s] = (floatx4){bias2[s], bias2[s], bias2[s], bias2[s]};
        #pragma unroll
        for (int kt = 0; kt < 4; ++kt) {
            short8 A[4];
            #pragma unroll
            for (int mt = 0; mt < 4; ++mt)
                A[mt] = *(const short8*)&sM[(mt*16 + l16) * SM_LD + kt*32 + quad*8];
            #pragma unroll
            for (int mt = 0; mt < 4; ++mt)
                #pragma unroll
                for (int s = 0; s < 2; ++s)
                    acc2[mt][s] = __builtin_amdgcn_mfma_f32_16x16x32_bf16(
                        A[mt], B2f[s][kt], acc2[mt][s], 0, 0, 0);
        }
        __syncthreads();

        if (tid < TEM)
            s_att[tid] = sigm_f(s_p[0][tid] + s_p[1][tid] + s_p[2][tid] + s_p[3][tid] + ab0);
        __syncthreads();

        // scatter: agg[row_node] += silu(m2) * att   (fused from accumulators)
        #pragma unroll
        for (int mt = 0; mt < 4; ++mt)
            #pragma unroll
            for (int s = 0; s < 2; ++s)
                #pragma unroll
                for (int r = 0; r < 4; ++r) {
                    int edge = mt*16 + quad*4 + r;
                    int col  = (2*wv + s)*16 + l16;
                    float v  = silu_f(acc2[mt][s][r]) * s_att[edge];
                    atomicAdd(&agg[(size_t)s_r[edge] * H1 + col], v);
                }
    }
}

// ---------------------------------------------------------------- node update (residual MLP)
__global__ __launch_bounds__(128) void k_node(
    const float* __restrict__ na, const float* __restrict__ agg,
    const float* __restrict__ nw1, const float* __restrict__ nb1,
    const float* __restrict__ nw2, const float* __restrict__ nb2,
    float* __restrict__ h) {
    __shared__ float s_in[TN][340];
    __shared__ float s_h[TN][132];
    int tid = threadIdx.x;
    int n0  = blockIdx.x * TN;

    #pragma unroll 4
    for (int e = 0; e < TN; ++e) {
        int n = n0 + e;
        if (n < N_NODES) {
            s_in[e][tid]        = h[n * H1 + tid];
            s_in[e][H1 + tid]   = agg[n * H1 + tid];
            if (tid < F_STRUCT) s_in[e][2*H1 + tid] = na[n * F_NODE + tid];
        } else {
            s_in[e][tid] = 0.f; s_in[e][H1 + tid] = 0.f;
            if (tid < F_STRUCT) s_in[e][2*H1 + tid] = 0.f;
        }
    }
    __syncthreads();

    float acc[TN];
    {
        float bb = nb1[tid];
        #pragma unroll
        for (int e = 0; e < TN; ++e) acc[e] = bb;
    }
    for (int k = 0; k < 336; k += 4) {
        float w0 = nw1[(k+0)*H1 + tid];
        float w1 = nw1[(k+1)*H1 + tid];
        float w2 = nw1[(k+2)*H1 + tid];
        float w3 = nw1[(k+3)*H1 + tid];
        #pragma unroll
        for (int e = 0; e < TN; ++e) {
            const float4 x = *(const float4*)&s_in[e][k];
            acc[e] = fmaf(x.x, w0, acc[e]);
            acc[e] = fmaf(x.y, w1, acc[e]);
            acc[e] = fmaf(x.z, w2, acc[e]);
            acc[e] = fmaf(x.w, w3, acc[e]);
        }
    }
    {
        float w0 = nw1[336*H1 + tid];
        float w1 = nw1[337*H1 + tid];
        float w2 = nw1[338*H1 + tid];
        #pragma unroll
        for (int e = 0; e < TN; ++e) {
            acc[e] = fmaf(s_in[e][336], w0, acc[e]);
            acc[e] = fmaf(s_in[e][337], w1, acc[e]);
            acc[e] = fmaf(s_in[e][338], w2, acc[e]);
        }
    }
    #pragma unroll
    for (int e = 0; e < TN; ++e) s_h[e][tid] = silu_f(acc[e]);
    __syncthreads();

    {
        float bb = nb2[tid];
        #pragma unroll
        for (int e = 0; e < TN; ++e) acc[e] = bb;
    }
    for (int k = 0; k < H1; k += 4) {
        float w0 = nw2[(k+0)*H1 + tid];
        float w1 = nw2[(k+1)*H1 + tid];
        float w2 = nw2[(k+2)*H1 + tid];
        float w3 = nw2[(k+3)*H1 + tid];
        #pragma unroll
        for (int e = 0; e < TN; ++e) {
            const float4 x = *(const float4*)&s_h[e][k];
            acc[e] = fmaf(x.x, w0, acc[e]);
            acc[e] = fmaf(x.y, w1, acc[e]);
            acc[e] = fmaf(x.z, w2, acc[e]);
            acc[e] = fmaf(x.w, w3, acc[e]);
        }
    }
    #pragma unroll 4
    for (int e = 0; e < TN; ++e) {
        int n = n0 + e;
        if (n < N_NODES) h[n * H1 + tid] = s_in[e][tid] + acc[e];
    }
}

// ---------------------------------------------------------------- decoder
__global__ __launch_bounds__(128) void k_dec(
    const float* __restrict__ h,
    const float* __restrict__ w1, const float* __restrict__ b1,
    const float* __restrict__ w2, const float* __restrict__ b2,
    float* __restrict__ hdec) {
    __shared__ float s_in[TN][132];
    __shared__ float s_h[TN][132];
    int tid = threadIdx.x;
    int n0  = blockIdx.x * TN;

    #pragma unroll 4
    for (int e = 0; e < TN; ++e) {
        int n = n0 + e;
        s_in[e][tid] = (n < N_NODES) ? h[n * H1 + tid] : 0.f;
    }
    __syncthreads();

    float acc[TN];
    {
        float bb = b1[tid];
        #pragma unroll
        for (int e = 0; e < TN; ++e) acc[e] = bb;
    }
    for (int k = 0; k < H1; k += 4) {
        float w0  = w1[(k+0)*H1 + tid];
        float w1_ = w1[(k+1)*H1 + tid];
        float w2_ = w1[(k+2)*H1 + tid];
        float w3  = w1[(k+3)*H1 + tid];
        #pragma unroll
        for (int e = 0; e < TN; ++e) {
            const float4 x = *(const float4*)&s_in[e][k];
            acc[e] = fmaf(x.x, w0, acc[e]);
            acc[e] = fmaf(x.y, w1_, acc[e]);
            acc[e] = fmaf(x.z, w2_, acc[e]);
            acc[e] = fmaf(x.w, w3, acc[e]);
        }
    }
    #pragma unroll
    for (int e = 0; e < TN; ++e) s_h[e][tid] = silu_f(acc[e]);
    __syncthreads();

    {
        float bb = b2[tid];
        #pragma unroll
        for (int e = 0; e < TN; ++e) acc[e] = bb;
    }
    for (int k = 0; k < H1; k += 4) {
        float w0  = w2[(k+0)*H1 + tid];
        float w1_ = w2[(k+1)*H1 + tid];
        float w2_ = w2[(k+2)*H1 + tid];
        float w3  = w2[(k+3)*H1 + tid];
        #pragma unroll
        for (int e = 0; e < TN; ++e) {
            const float4 x = *(const float4*)&s_h[e][k];
            acc[e] = fmaf(x.x, w0, acc[e]);
            acc[e] = fmaf(x.y, w1_, acc[e]);
            acc[e] = fmaf(x.z, w2_, acc[e]);
            acc[e] = fmaf(x.w, w3, acc[e]);
        }
    }
    #pragma unroll 4
    for (int e = 0; e < TN; ++e) {
        int n = n0 + e;
        if (n < N_NODES) hdec[n * H1 + tid] = acc[e];
    }
}

// ---------------------------------------------------------------- ESM FFNN via MFMA: 1280 -> 256(relu) -> 64(relu)
__global__ __launch_bounds__(256, 2) void k_ffnn_mfma(
    const float* __restrict__ na,
    const unsigned short* __restrict__ wb1,   // [160][256] packed short8
    const float* __restrict__ b1,
    const unsigned short* __restrict__ wb2,   // [32][64] packed short8
    const float* __restrict__ b2,
    float* __restrict__ esm) {

    __shared__ unsigned short sA[TFM * SA_LD];   // 17408 B
    __shared__ unsigned short sH[TFM * SH_LD];   // 33792 B

    const int tid  = threadIdx.x;
    const int wv   = tid >> 6;
    const int lane = tid & 63;
    const int l16  = lane & 15;
    const int quad = lane >> 4;
    const int n0   = blockIdx.x * TFM;

    floatx4 acc[4][4];
    #pragma unroll
    for (int s = 0; s < 4; ++s) {
        float bb = b1[wv * 64 + s * 16 + l16];
        #pragma unroll
        for (int mt = 0; mt < 4; ++mt)
            acc[mt][s] = (floatx4){bb, bb, bb, bb};
    }

    for (int c = 0; c < 10; ++c) {
        __syncthreads();
        #pragma unroll
        for (int i = 0; i < 8; ++i) {
            int idx = i * 256 + tid;
            int row = idx >> 5;
            int k0  = (idx & 31) * 4;
            float v0 = 0.f, v1 = 0.f, v2 = 0.f, v3 = 0.f;
            int nn = n0 + row;
            if (nn < N_NODES) {
                const float* p = na + (size_t)nn * F_NODE + F_STRUCT + c * 128 + k0;
                v0 = p[0]; v1 = p[1]; v2 = p[2]; v3 = p[3];
            }
            unsigned int lo = (unsigned)f2bf(v0) | ((unsigned)f2bf(v1) << 16);
            unsigned int hi = (unsigned)f2bf(v2) | ((unsigned)f2bf(v3) << 16);
            *(uint2*)&sA[row * SA_LD + k0] = make_uint2(lo, hi);
        }
        __syncthreads();

        #pragma unroll
        for (int kt2 = 0; kt2 < 4; ++kt2) {
            const int kt = c * 4 + kt2;
            short8 A[4], B[4];
            #pragma unroll
            for (int mt = 0; mt < 4; ++mt)
                A[mt] = *(const short8*)&sA[(mt*16 + l16) * SA_LD + kt2*32 + quad*8];
            #pragma unroll
            for (int s = 0; s < 4; ++s)
                B[s] = *(const short8*)&wb1[((size_t)(kt*4 + quad) * 256 + wv*64 + s*16 + l16) * 8];
            #pragma unroll
            for (int mt = 0; mt < 4; ++mt)
                #pragma unroll
                for (int s = 0; s < 4; ++s)
                    acc[mt][s] = __builtin_amdgcn_mfma_f32_16x16x32_bf16(
                        A[mt], B[s], acc[mt][s], 0, 0, 0);
        }
    }

    #pragma unroll
    for (int mt = 0; mt < 4; ++mt)
        #pragma unroll
        for (int s = 0; s < 4; ++s)
            #pragma unroll
            for (int r = 0; r < 4; ++r) {
                int row = mt*16 + quad*4 + r;
                int col = wv*64 + s*16 + l16;
                sH[row * SH_LD + col] = f2bf(fmaxf(acc[mt][s][r], 0.f));
            }
    __syncthreads();

    floatx4 acc2[4];
    #pragma unroll
    for (int s = 0; s < 4; ++s) {
        float bb = b2[s * 16 + l16];
        acc2[s] = (floatx4){bb, bb, bb, bb};
    }
    #pragma unroll
    for (int kt = 0; kt < 8; ++kt) {
        short8 A = *(const short8*)&sH[(wv*16 + l16) * SH_LD + kt*32 + quad*8];
        #pragma unroll
        for (int s = 0; s < 4; ++s) {
            short8 B = *(const short8*)&wb2[((size_t)(kt*4 + quad) * 64 + s*16 + l16) * 8];
            acc2[s] = __builtin_amdgcn_mfma_f32_16x16x32_bf16(A, B, acc2[s], 0, 0, 0);
        }
    }
    #pragma unroll
    for (int s = 0; s < 4; ++s)
        #pragma unroll
        for (int r = 0; r < 4; ++r) {
            int nn = n0 + wv*16 + quad*4 + r;
            if (nn < N_NODES)
                esm[(size_t)nn * H2 + s*16 + l16] = fmaxf(acc2[s][r], 0.f);
        }
}

// ---------------------------------------------------------------- last head
__global__ __launch_bounds__(192) void k_last(
    const float* __restrict__ hdec, const float* __restrict__ esm,
    const float* __restrict__ w1, const float* __restrict__ b1,
    const float* __restrict__ w2, const float* __restrict__ b2,
    float* __restrict__ out) {
    __shared__ float s_in[TN][196];
    __shared__ float s_h[TN][196];
    __shared__ float s_w2[192];
    int tid = threadIdx.x;
    int n0  = blockIdx.x * TN;

    s_w2[tid] = w2[tid];
    #pragma unroll 4
    for (int e = 0; e < TN; ++e) {
        int n = n0 + e;
        if (n < N_NODES) {
            s_in[e][tid] = (tid < H1) ? hdec[n * H1 + tid] : esm[n * H2 + (tid - H1)];
        } else {
            s_in[e][tid] = 0.f;
        }
    }
    __syncthreads();

    float acc[TN];
    {
        float bb = b1[tid];
        #pragma unroll
        for (int e = 0; e < TN; ++e) acc[e] = bb;
    }
    for (int k = 0; k < 192; k += 4) {
        float w0  = w1[(k+0)*192 + tid];
        float w1_ = w1[(k+1)*192 + tid];
        float w2_ = w1[(k+2)*192 + tid];
        float w3  = w1[(k+3)*192 + tid];
        #pragma unroll
        for (int e = 0; e < TN; ++e) {
            const float4 x = *(const float4*)&s_in[e][k];
            acc[e] = fmaf(x.x, w0, acc[e]);
            acc[e] = fmaf(x.y, w1_, acc[e]);
            acc[e] = fmaf(x.z, w2_, acc[e]);
            acc[e] = fmaf(x.w, w3, acc[e]);
        }
    }
    #pragma unroll
    for (int e = 0; e < TN; ++e) s_h[e][tid] = silu_f(acc[e]);
    __syncthreads();

    if (tid < TN) {
        int n = n0 + tid;
        if (n < N_NODES) {
            float s = 0.f;
            for (int j = 0; j < 192; ++j) s = fmaf(s_h[tid][j], s_w2[j], s);
            out[n] = sigm_f(s + b2[0]);
        }
    }
}

// ----------------------------------------------------------------
extern "C" void kernel_launch(void* const* d_in, const int* in_sizes, int n_in,
                              void* d_out, int out_size, void* d_ws, size_t ws_size,
                              hipStream_t stream) {
    const float* na      = (const float*)d_in[0];
    const float* coords  = (const float*)d_in[1];
    const int*   ei      = (const int*)  d_in[2];
    const float* ea      = (const float*)d_in[3];
    const float* emb_w   = (const float*)d_in[4];
    const float* emb_b   = (const float*)d_in[5];
    const float* edge_w1 = (const float*)d_in[6];
    const float* edge_b1 = (const float*)d_in[7];
    const float* edge_w2 = (const float*)d_in[8];
    const float* edge_b2 = (const float*)d_in[9];
    const float* att_w   = (const float*)d_in[10];
    const float* att_b   = (const float*)d_in[11];
    const float* node_w1 = (const float*)d_in[12];
    const float* node_b1 = (const float*)d_in[13];
    const float* node_w2 = (const float*)d_in[14];
    const float* node_b2 = (const float*)d_in[15];
    const float* dec_w1  = (const float*)d_in[16];
    const float* dec_b1  = (const float*)d_in[17];
    const float* dec_w2  = (const float*)d_in[18];
    const float* dec_b2  = (const float*)d_in[19];
    const float* ffnn_w1 = (const float*)d_in[20];
    const float* ffnn_b1 = (const float*)d_in[21];
    const float* ffnn_w2 = (const float*)d_in[22];
    const float* ffnn_b2 = (const float*)d_in[23];
    const float* last_w1 = (const float*)d_in[24];
    const float* last_b1 = (const float*)d_in[25];
    const float* last_w2 = (const float*)d_in[26];
    const float* last_b2 = (const float*)d_in[27];

    // workspace: h | agg = exactly 51.2 MB (ws_size is known to be < 54.4 MB — do not grow)
    const size_t need = 2ull * N_NODES * H1 * sizeof(float);
    if (ws_size < need) return;

    float* h    = (float*)d_ws;
    float* agg  = h + (size_t)N_NODES * H1;
    float* hdec = agg;
    float* esm  = h;                       // esm uses h[0 .. 3.2M floats) (12.8 MB)
    float* out  = (float*)d_out;

    // packed bf16 ffnn weights live in the tail of h, which is dead after k_dec:
    //   wb1 at float offset 4,194,304 (16 MB): 163840 floats (655 KB)
    //   wb2 right after: 4096 floats (16 KB). h region is 6.4M floats — no overlap with esm.
    unsigned short* wb1 = (unsigned short*)(h + 4194304);
    unsigned short* wb2 = (unsigned short*)(h + 4194304 + 163840);

    // packed bf16 edge-GEMM2 weights (per layer, 32 KB) live in d_out, which is
    // dead until k_last fully rewrites it at the end.
    unsigned short* wb2e = (unsigned short*)d_out;

    int nblk  = (N_NODES + TN - 1) / TN;
    int nblkF = (N_NODES + TFM - 1) / TFM;   // 782
    int n4    = N_NODES * H1 / 4;

    k_emb<<<N_NODES, H1, 0, stream>>>(na, emb_w, emb_b, h);

    for (int i = 0; i < 4; ++i) {
        k_zero<<<(n4 + 255) / 256, 256, 0, stream>>>((float4*)agg, n4);
        k_cvt_pack<<<8, 256, 0, stream>>>(edge_w2 + (size_t)i * H1 * H1, wb2e, 16 * H1, 7);
        k_edge_mfma<<<GRID_E, 256, 0, stream>>>(
            h, ei, coords, ea,
            edge_w1 + (size_t)i * 258 * H1, edge_b1 + i * H1,
            wb2e,  edge_b2 + i * H1,
            att_w + i * H1, att_b + i, agg);
        k_node<<<nblk, 128, 0, stream>>>(
            na, agg,
            node_w1 + (size_t)i * 339 * H1, node_b1 + i * H1,
            node_w2 + (size_t)i * H1 * H1,  node_b2 + i * H1, h);
    }

    k_dec<<<nblk, 128, 0, stream>>>(h, dec_w1, dec_b1, dec_w2, dec_b2, hdec);

    // h is now dead except esm region -> pack ffnn weights into its tail, then MFMA ffnn
    k_cvt_pack<<<160, 256, 0, stream>>>(ffnn_w1, wb1, 160 * 256, 8);   // 1280x256
    k_cvt_pack<<<8,   256, 0, stream>>>(ffnn_w2, wb2, 32 * 64,   6);   // 256x64
    k_ffnn_mfma<<<nblkF, 256, 0, stream>>>(na, wb1, ffnn_b1, wb2, ffnn_b2, esm);

    k_last<<<nblk, 192, 0, stream>>>(hdec, esm, last_w1, last_b1, last_w2, last_b2, out);
}

// Round 3
// 2988.845 us; speedup vs baseline: 1.8795x; 1.8795x over previous
//
#include <hip/hip_runtime.h>
#include <hip/hip_bf16.h>

#define N_NODES 50000
#define N_EDGES 800000
#define F_NODE  1363
#define F_STRUCT 83
#define F_ESM   1280
#define H1      128
#define H2      64
#define TN      32    // nodes per block (non-edge kernels)

// edge-kernel tiling
#define TEM      64                 // edges per tile
#define NTILES   (N_EDGES / TEM)    // 12500
#define GRID_E   512                // persistent blocks (2 per CU)
#define SIN_LD   296                // 288 + 8 pad: stride 148 dwords -> 2-way (free) LDS pattern
#define SM_LD    136                // 128 + 8 pad: stride 68 dwords -> 2-way (free)

// ffnn MFMA tiling
#define TFM      64                 // nodes per ffnn/node block
#define SA_LD    136                // 128 + 8 shorts
#define SH_LD    264                // 256 + 8 shorts
#define SNI_LD   360                // 352 + 8 shorts (node input, K padded 339->352)

typedef __attribute__((ext_vector_type(8))) short short8;   // 8 x bf16 (4 VGPRs)
typedef __attribute__((ext_vector_type(4))) float floatx4;  // MFMA accumulator

__device__ __forceinline__ float silu_f(float x) { return x / (1.f + __expf(-x)); }
__device__ __forceinline__ float sigm_f(float x) { return 1.f / (1.f + __expf(-x)); }

// fp32 -> bf16 bits, round-to-nearest-even (finite inputs only)
__device__ __forceinline__ unsigned short f2bf(float f) {
    unsigned int u = __float_as_uint(f);
    unsigned int r = (u + 0x7FFFu + ((u >> 16) & 1u)) >> 16;
    return (unsigned short)r;
}
// packed bf16x2 -> floats
__device__ __forceinline__ float bflo(unsigned int u) { return __uint_as_float(u << 16); }
__device__ __forceinline__ float bfhi(unsigned int u) { return __uint_as_float(u & 0xFFFF0000u); }

// ---------------------------------------------------------------- zero-fill
__global__ void k_zero(float4* __restrict__ p, int n4) {
    int i = blockIdx.x * 256 + threadIdx.x;
    if (i < n4) p[i] = make_float4(0.f, 0.f, 0.f, 0.f);
}

// ---------------------------------------------------------------- h = h0 @ emb_w + emb_b
__global__ __launch_bounds__(H1) void k_emb(const float* __restrict__ na,
                                            const float* __restrict__ w,
                                            const float* __restrict__ b,
                                            float* __restrict__ h) {
    __shared__ float s0[F_STRUCT];
    int n = blockIdx.x, tid = threadIdx.x;
    if (tid < F_STRUCT) s0[tid] = na[n * F_NODE + tid];
    __syncthreads();
    float acc = b[tid];
    for (int k = 0; k < F_STRUCT; ++k)
        acc = fmaf(s0[k], w[k * H1 + tid], acc);
    h[n * H1 + tid] = acc;
}

// ---------------------------------------------------------------- pack fp32 [K x N] -> bf16 B-fragment order
// dst[(k/8)*N + n] is a short8 holding w[k/8*8 + j][n], j=0..7  (one 16B load per MFMA B-frag)
__global__ __launch_bounds__(256) void k_cvt_pack(const float* __restrict__ src,
                                                  unsigned short* __restrict__ dst,
                                                  int total, int logn) {
    int gid = blockIdx.x * 256 + threadIdx.x;
    if (gid >= total) return;
    int n   = 1 << logn;
    int kb  = gid >> logn;
    int col = gid & (n - 1);
    short8 v;
    #pragma unroll
    for (int j = 0; j < 8; ++j)
        v[j] = (short)f2bf(src[(kb * 8 + j) * n + col]);
    *(short8*)&dst[(size_t)gid * 8] = v;
}

// pack with K zero-padding: src is [Ksrc x 128], dst covers kb = 0..total/128-1
__global__ __launch_bounds__(256) void k_cvt_pad(const float* __restrict__ src,
                                                 unsigned short* __restrict__ dst,
                                                 int Ksrc, int total) {
    int gid = blockIdx.x * 256 + threadIdx.x;
    if (gid >= total) return;
    int kb  = gid >> 7;
    int col = gid & 127;
    short8 v;
    #pragma unroll
    for (int j = 0; j < 8; ++j) {
        int k = kb * 8 + j;
        v[j] = (short)((k < Ksrc) ? f2bf(src[k * H1 + col]) : 0);
    }
    *(short8*)&dst[(size_t)gid * 8] = v;
}

// ---------------------------------------------------------------- edge MLP via MFMA bf16
// (round-1 proven config: 2 blocks/CU, B1+B2 in registers, K=288)
// mfma_f32_16x16x32_bf16 layouts (verified, learn_hip m89/m91/m120):
//   A[m = lane&15][k = (lane>>4)*8 + j]   (short8, j=0..7)
//   B[k = (lane>>4)*8 + j][n = lane&15]
//   D: col = lane&15, row = (lane>>4)*4 + reg
__global__ __launch_bounds__(256, 2) void k_edge_mfma(
    const float* __restrict__ h, const int* __restrict__ ei,
    const float* __restrict__ coords, const float* __restrict__ ea,
    const float* __restrict__ ew1, const float* __restrict__ eb1,
    const float* __restrict__ ew2, const float* __restrict__ eb2,
    const float* __restrict__ aw,  const float* __restrict__ ab,
    float* __restrict__ agg) {

    __shared__ unsigned short sIn[TEM * SIN_LD];   // 37888 B
    __shared__ unsigned short sM [TEM * SM_LD];    // 17408 B
    __shared__ float s_aw[H1];
    __shared__ float s_p[4][TEM];
    __shared__ float s_att[TEM];
    __shared__ int   s_r[TEM], s_c[TEM];

    const int tid  = threadIdx.x;
    const int wv   = tid >> 6;
    const int lane = tid & 63;
    const int l16  = lane & 15;
    const int quad = lane >> 4;

    if (tid < H1) s_aw[tid] = aw[tid];
    // zero the pad cols [258..295] once; never rewritten (MFMA must not see NaN garbage)
    for (int i = tid; i < TEM * (SIN_LD - 258); i += 256) {
        int r = i / (SIN_LD - 258), c = i % (SIN_LD - 258);
        sIn[r * SIN_LD + 258 + c] = 0;
    }

    // ---- load B-fragments (weights) once per block into registers
    short8 B1[2][9];   // GEMM1: K=288 (zero-padded past 258), N-slice per (wv,s)
    short8 B2[2][4];   // GEMM2: K=128
    float  bias1[2], bias2[2];
    #pragma unroll
    for (int s = 0; s < 2; ++s) {
        const int n = (2 * wv + s) * 16 + l16;
        bias1[s] = eb1[n];
        bias2[s] = eb2[n];
        #pragma unroll
        for (int kt = 0; kt < 9; ++kt) {
            short8 f;
            #pragma unroll
            for (int j = 0; j < 8; ++j) {
                int k = kt * 32 + quad * 8 + j;
                float v = (k < 258) ? ew1[k * H1 + n] : 0.f;
                f[j] = (short)f2bf(v);
            }
            B1[s][kt] = f;
        }
        #pragma unroll
        for (int kt = 0; kt < 4; ++kt) {
            short8 f;
            #pragma unroll
            for (int j = 0; j < 8; ++j) {
                int k = kt * 32 + quad * 8 + j;
                f[j] = (short)f2bf(ew2[k * H1 + n]);
            }
            B2[s][kt] = f;
        }
    }
    const float ab0 = ab[0];

    for (int t = blockIdx.x; t < NTILES; t += GRID_E) {
        const int e0 = t * TEM;
        __syncthreads();   // previous iteration fully done with shared state

        if (tid < TEM) {
            int r = ei[e0 + tid], c = ei[N_EDGES + e0 + tid];
            s_r[tid] = r; s_c[tid] = c;
            float dx = coords[r*3+0] - coords[c*3+0];
            float dy = coords[r*3+1] - coords[c*3+1];
            float dz = coords[r*3+2] - coords[c*3+2];
            sIn[tid * SIN_LD + 256] = f2bf(dx*dx + dy*dy + dz*dz);
            sIn[tid * SIN_LD + 257] = f2bf(ea[e0 + tid]);
        }
        __syncthreads();

        // gather: edge_in[e][0:128]=h[row], [128:256]=h[col], fp32 -> bf16
        #pragma unroll
        for (int i = 0; i < 16; ++i) {
            int idx  = i * 256 + tid;
            int e    = idx >> 6;
            int part = idx & 63;
            const float* src = (part < 32)
                ? (h + (size_t)s_r[e] * H1 + part * 4)
                : (h + (size_t)s_c[e] * H1 + (part - 32) * 4);
            float4 x = *(const float4*)src;
            unsigned int lo = (unsigned)f2bf(x.x) | ((unsigned)f2bf(x.y) << 16);
            unsigned int hi = (unsigned)f2bf(x.z) | ((unsigned)f2bf(x.w) << 16);
            *(uint2*)&sIn[e * SIN_LD + part * 4] = make_uint2(lo, hi);
        }
        __syncthreads();

        // ---- GEMM1: acc[mt][s] = edge_in @ ew1 + b1
        floatx4 acc[4][2];
        #pragma unroll
        for (int mt = 0; mt < 4; ++mt)
            #pragma unroll
            for (int s = 0; s < 2; ++s)
                acc[mt][s] = (floatx4){bias1[s], bias1[s], bias1[s], bias1[s]};
        #pragma unroll
        for (int kt = 0; kt < 9; ++kt) {
            short8 A[4];
            #pragma unroll
            for (int mt = 0; mt < 4; ++mt)
                A[mt] = *(const short8*)&sIn[(mt*16 + l16) * SIN_LD + kt*32 + quad*8];
            #pragma unroll
            for (int mt = 0; mt < 4; ++mt)
                #pragma unroll
                for (int s = 0; s < 2; ++s)
                    acc[mt][s] = __builtin_amdgcn_mfma_f32_16x16x32_bf16(
                        A[mt], B1[s][kt], acc[mt][s], 0, 0, 0);
        }
        // silu -> sM (bf16 A-operand of GEMM2)
        #pragma unroll
        for (int mt = 0; mt < 4; ++mt)
            #pragma unroll
            for (int s = 0; s < 2; ++s)
                #pragma unroll
                for (int r = 0; r < 4; ++r) {
                    int row = mt*16 + quad*4 + r;
                    int col = (2*wv + s)*16 + l16;
                    sM[row * SM_LD + col] = f2bf(silu_f(acc[mt][s][r]));
                }
        __syncthreads();

        // attention partials (VALU) — independent of GEMM2 (MFMA), both read sM
        {
            int e = tid & 63, part = tid >> 6;
            const uint2* pm  = (const uint2*)&sM[e * SM_LD + part * 32];
            const float* paw = &s_aw[part * 32];
            float ssum = 0.f;
            #pragma unroll
            for (int j = 0; j < 8; ++j) {
                uint2 u = pm[j];
                ssum = fmaf(bflo(u.x), paw[4*j+0], ssum);
                ssum = fmaf(bfhi(u.x), paw[4*j+1], ssum);
                ssum = fmaf(bflo(u.y), paw[4*j+2], ssum);
                ssum = fmaf(bfhi(u.y), paw[4*j+3], ssum);
            }
            s_p[part][e] = ssum;
        }

        // ---- GEMM2: acc2[mt][s] = m @ ew2 + b2
        floatx4 acc2[4][2];
        #pragma unroll
        for (int mt = 0; mt < 4; ++mt)
            #pragma unroll
            for (int s = 0; s < 2; ++s)
                acc2[mt][s] = (floatx4){bias2[s], bias2[s], bias2[s], bias2[s]};
        #pragma unroll
        for (int kt = 0; kt < 4; ++kt) {
            short8 A[4];
            #pragma unroll
            for (int mt = 0; mt < 4; ++mt)
                A[mt] = *(const short8*)&sM[(mt*16 + l16) * SM_LD + kt*32 + quad*8];
            #pragma unroll
            for (int mt = 0; mt < 4; ++mt)
                #pragma unroll
                for (int s = 0; s < 2; ++s)
                    acc2[mt][s] = __builtin_amdgcn_mfma_f32_16x16x32_bf16(
                        A[mt], B2[s][kt], acc2[mt][s], 0, 0, 0);
        }
        __syncthreads();

        if (tid < TEM)
            s_att[tid] = sigm_f(s_p[0][tid] + s_p[1][tid] + s_p[2][tid] + s_p[3][tid] + ab0);
        __syncthreads();

        // scatter: agg[row_node] += silu(m2) * att   (fused from accumulators)
        #pragma unroll
        for (int mt = 0; mt < 4; ++mt)
            #pragma unroll
            for (int s = 0; s < 2; ++s)
                #pragma unroll
                for (int r = 0; r < 4; ++r) {
                    int edge = mt*16 + quad*4 + r;
                    int col  = (2*wv + s)*16 + l16;
                    float v  = silu_f(acc2[mt][s][r]) * s_att[edge];
                    atomicAdd(&agg[(size_t)s_r[edge] * H1 + col], v);
                }
    }
}

// ---------------------------------------------------------------- node update via MFMA bf16
// h = h + silu(concat(h,agg,h0) @ nw1 + nb1) @ nw2 + nb2
// GEMM1: [64 x 352(pad of 339)] @ [352 x 128]; GEMM2: [64 x 128] @ [128 x 128].
// Weights streamed per-kt from pre-packed bf16 fragments (L2-resident, 123 KB).
// Residual uses fp32 h re-read from global (not the bf16-staged copy).
__global__ __launch_bounds__(256, 2) void k_node_mfma(
    const float* __restrict__ na, const float* __restrict__ agg,
    const unsigned short* __restrict__ wb1, const float* __restrict__ b1,
    const unsigned short* __restrict__ wb2, const float* __restrict__ b2,
    float* h) {

    __shared__ unsigned short sIn[TFM * SNI_LD];  // 46080 B
    __shared__ unsigned short sH [TFM * SM_LD];   // 17408 B  (total 63488 -> 2 blocks/CU)

    const int tid  = threadIdx.x;
    const int wv   = tid >> 6;
    const int lane = tid & 63;
    const int l16  = lane & 15;
    const int quad = lane >> 4;
    const int n0   = blockIdx.x * TFM;

    // stage cols 0..127 = h, 128..255 = agg (fp32 -> bf16, float4 loads)
    #pragma unroll
    for (int i = 0; i < 8; ++i) {
        int idx = i * 256 + tid;          // 0..2047
        int row = idx >> 5;               // 0..63
        int g   = (idx & 31) * 4;         // 0..124
        int nn  = n0 + row;
        float4 x = make_float4(0.f,0.f,0.f,0.f), y = make_float4(0.f,0.f,0.f,0.f);
        if (nn < N_NODES) {
            x = *(const float4*)&h[(size_t)nn * H1 + g];
            y = *(const float4*)&agg[(size_t)nn * H1 + g];
        }
        *(uint2*)&sIn[row * SNI_LD + g] = make_uint2(
            (unsigned)f2bf(x.x) | ((unsigned)f2bf(x.y) << 16),
            (unsigned)f2bf(x.z) | ((unsigned)f2bf(x.w) << 16));
        *(uint2*)&sIn[row * SNI_LD + H1 + g] = make_uint2(
            (unsigned)f2bf(y.x) | ((unsigned)f2bf(y.y) << 16),
            (unsigned)f2bf(y.z) | ((unsigned)f2bf(y.w) << 16));
    }
    // stage cols 256..351: h0 (83 cols of na) + zero pad
    #pragma unroll
    for (int i = 0; i < 24; ++i) {
        int idx = i * 256 + tid;          // 0..6143 = 64 rows x 96 cols
        int row = idx / 96;
        int c   = idx - row * 96;
        int nn  = n0 + row;
        float v = (nn < N_NODES && c < F_STRUCT) ? na[(size_t)nn * F_NODE + c] : 0.f;
        sIn[row * SNI_LD + 256 + c] = f2bf(v);
    }
    __syncthreads();

    // GEMM1: each wave owns 32 output cols (wv*32 .. wv*32+31), all 64 rows
    floatx4 acc[4][2];
    #pragma unroll
    for (int s = 0; s < 2; ++s) {
        float bb = b1[wv * 32 + s * 16 + l16];
        #pragma unroll
        for (int mt = 0; mt < 4; ++mt)
            acc[mt][s] = (floatx4){bb, bb, bb, bb};
    }
    #pragma unroll
    for (int kt = 0; kt < 11; ++kt) {
        short8 A[4], B[2];
        #pragma unroll
        for (int mt = 0; mt < 4; ++mt)
            A[mt] = *(const short8*)&sIn[(mt*16 + l16) * SNI_LD + kt*32 + quad*8];
        #pragma unroll
        for (int s = 0; s < 2; ++s)
            B[s] = *(const short8*)&wb1[((size_t)(kt*4 + quad) * H1 + wv*32 + s*16 + l16) * 8];
        #pragma unroll
        for (int mt = 0; mt < 4; ++mt)
            #pragma unroll
            for (int s = 0; s < 2; ++s)
                acc[mt][s] = __builtin_amdgcn_mfma_f32_16x16x32_bf16(
                    A[mt], B[s], acc[mt][s], 0, 0, 0);
    }

    // silu -> sH (bf16 A-operand of GEMM2)
    #pragma unroll
    for (int mt = 0; mt < 4; ++mt)
        #pragma unroll
        for (int s = 0; s < 2; ++s)
            #pragma unroll
            for (int r = 0; r < 4; ++r) {
                int row = mt*16 + quad*4 + r;
                int col = wv*32 + s*16 + l16;
                sH[row * SM_LD + col] = f2bf(silu_f(acc[mt][s][r]));
            }
    __syncthreads();

    // GEMM2
    floatx4 acc2[4][2];
    #pragma unroll
    for (int s = 0; s < 2; ++s) {
        float bb = b2[wv * 32 + s * 16 + l16];
        #pragma unroll
        for (int mt = 0; mt < 4; ++mt)
            acc2[mt][s] = (floatx4){bb, bb, bb, bb};
    }
    #pragma unroll
    for (int kt = 0; kt < 4; ++kt) {
        short8 A[4], B[2];
        #pragma unroll
        for (int mt = 0; mt < 4; ++mt)
            A[mt] = *(const short8*)&sH[(mt*16 + l16) * SM_LD + kt*32 + quad*8];
        #pragma unroll
        for (int s = 0; s < 2; ++s)
            B[s] = *(const short8*)&wb2[((size_t)(kt*4 + quad) * H1 + wv*32 + s*16 + l16) * 8];
        #pragma unroll
        for (int mt = 0; mt < 4; ++mt)
            #pragma unroll
            for (int s = 0; s < 2; ++s)
                acc2[mt][s] = __builtin_amdgcn_mfma_f32_16x16x32_bf16(
                    A[mt], B[s], acc2[mt][s], 0, 0, 0);
    }

    // residual: h += delta   (fp32 h re-read from global; same rows this block staged)
    #pragma unroll
    for (int mt = 0; mt < 4; ++mt)
        #pragma unroll
        for (int s = 0; s < 2; ++s)
            #pragma unroll
            for (int r = 0; r < 4; ++r) {
                int row = mt*16 + quad*4 + r;
                int col = wv*32 + s*16 + l16;
                int nn  = n0 + row;
                if (nn < N_NODES) {
                    size_t off = (size_t)nn * H1 + col;
                    h[off] = h[off] + acc2[mt][s][r];
                }
            }
}

// ---------------------------------------------------------------- decoder
__global__ __launch_bounds__(128) void k_dec(
    const float* __restrict__ h,
    const float* __restrict__ w1, const float* __restrict__ b1,
    const float* __restrict__ w2, const float* __restrict__ b2,
    float* __restrict__ hdec) {
    __shared__ float s_in[TN][132];
    __shared__ float s_h[TN][132];
    int tid = threadIdx.x;
    int n0  = blockIdx.x * TN;

    #pragma unroll 4
    for (int e = 0; e < TN; ++e) {
        int n = n0 + e;
        s_in[e][tid] = (n < N_NODES) ? h[n * H1 + tid] : 0.f;
    }
    __syncthreads();

    float acc[TN];
    {
        float bb = b1[tid];
        #pragma unroll
        for (int e = 0; e < TN; ++e) acc[e] = bb;
    }
    for (int k = 0; k < H1; k += 4) {
        float w0  = w1[(k+0)*H1 + tid];
        float w1_ = w1[(k+1)*H1 + tid];
        float w2_ = w1[(k+2)*H1 + tid];
        float w3  = w1[(k+3)*H1 + tid];
        #pragma unroll
        for (int e = 0; e < TN; ++e) {
            const float4 x = *(const float4*)&s_in[e][k];
            acc[e] = fmaf(x.x, w0, acc[e]);
            acc[e] = fmaf(x.y, w1_, acc[e]);
            acc[e] = fmaf(x.z, w2_, acc[e]);
            acc[e] = fmaf(x.w, w3, acc[e]);
        }
    }
    #pragma unroll
    for (int e = 0; e < TN; ++e) s_h[e][tid] = silu_f(acc[e]);
    __syncthreads();

    {
        float bb = b2[tid];
        #pragma unroll
        for (int e = 0; e < TN; ++e) acc[e] = bb;
    }
    for (int k = 0; k < H1; k += 4) {
        float w0  = w2[(k+0)*H1 + tid];
        float w1_ = w2[(k+1)*H1 + tid];
        float w2_ = w2[(k+2)*H1 + tid];
        float w3  = w2[(k+3)*H1 + tid];
        #pragma unroll
        for (int e = 0; e < TN; ++e) {
            const float4 x = *(const float4*)&s_h[e][k];
            acc[e] = fmaf(x.x, w0, acc[e]);
            acc[e] = fmaf(x.y, w1_, acc[e]);
            acc[e] = fmaf(x.z, w2_, acc[e]);
            acc[e] = fmaf(x.w, w3, acc[e]);
        }
    }
    #pragma unroll 4
    for (int e = 0; e < TN; ++e) {
        int n = n0 + e;
        if (n < N_NODES) hdec[n * H1 + tid] = acc[e];
    }
}

// ---------------------------------------------------------------- ESM FFNN via MFMA: 1280 -> 256(relu) -> 64(relu)
__global__ __launch_bounds__(256, 2) void k_ffnn_mfma(
    const float* __restrict__ na,
    const unsigned short* __restrict__ wb1,   // [160][256] packed short8
    const float* __restrict__ b1,
    const unsigned short* __restrict__ wb2,   // [32][64] packed short8
    const float* __restrict__ b2,
    float* __restrict__ esm) {

    __shared__ unsigned short sA[TFM * SA_LD];   // 17408 B
    __shared__ unsigned short sH[TFM * SH_LD];   // 33792 B

    const int tid  = threadIdx.x;
    const int wv   = tid >> 6;
    const int lane = tid & 63;
    const int l16  = lane & 15;
    const int quad = lane >> 4;
    const int n0   = blockIdx.x * TFM;

    floatx4 acc[4][4];
    #pragma unroll
    for (int s = 0; s < 4; ++s) {
        float bb = b1[wv * 64 + s * 16 + l16];
        #pragma unroll
        for (int mt = 0; mt < 4; ++mt)
            acc[mt][s] = (floatx4){bb, bb, bb, bb};
    }

    for (int c = 0; c < 10; ++c) {
        __syncthreads();
        #pragma unroll
        for (int i = 0; i < 8; ++i) {
            int idx = i * 256 + tid;
            int row = idx >> 5;
            int k0  = (idx & 31) * 4;
            float v0 = 0.f, v1 = 0.f, v2 = 0.f, v3 = 0.f;
            int nn = n0 + row;
            if (nn < N_NODES) {
                const float* p = na + (size_t)nn * F_NODE + F_STRUCT + c * 128 + k0;
                v0 = p[0]; v1 = p[1]; v2 = p[2]; v3 = p[3];
            }
            unsigned int lo = (unsigned)f2bf(v0) | ((unsigned)f2bf(v1) << 16);
            unsigned int hi = (unsigned)f2bf(v2) | ((unsigned)f2bf(v3) << 16);
            *(uint2*)&sA[row * SA_LD + k0] = make_uint2(lo, hi);
        }
        __syncthreads();

        #pragma unroll
        for (int kt2 = 0; kt2 < 4; ++kt2) {
            const int kt = c * 4 + kt2;
            short8 A[4], B[4];
            #pragma unroll
            for (int mt = 0; mt < 4; ++mt)
                A[mt] = *(const short8*)&sA[(mt*16 + l16) * SA_LD + kt2*32 + quad*8];
            #pragma unroll
            for (int s = 0; s < 4; ++s)
                B[s] = *(const short8*)&wb1[((size_t)(kt*4 + quad) * 256 + wv*64 + s*16 + l16) * 8];
            #pragma unroll
            for (int mt = 0; mt < 4; ++mt)
                #pragma unroll
                for (int s = 0; s < 4; ++s)
                    acc[mt][s] = __builtin_amdgcn_mfma_f32_16x16x32_bf16(
                        A[mt], B[s], acc[mt][s], 0, 0, 0);
        }
    }

    #pragma unroll
    for (int mt = 0; mt < 4; ++mt)
        #pragma unroll
        for (int s = 0; s < 4; ++s)
            #pragma unroll
            for (int r = 0; r < 4; ++r) {
                int row = mt*16 + quad*4 + r;
                int col = wv*64 + s*16 + l16;
                sH[row * SH_LD + col] = f2bf(fmaxf(acc[mt][s][r], 0.f));
            }
    __syncthreads();

    floatx4 acc2[4];
    #pragma unroll
    for (int s = 0; s < 4; ++s) {
        float bb = b2[s * 16 + l16];
        acc2[s] = (floatx4){bb, bb, bb, bb};
    }
    #pragma unroll
    for (int kt = 0; kt < 8; ++kt) {
        short8 A = *(const short8*)&sH[(wv*16 + l16) * SH_LD + kt*32 + quad*8];
        #pragma unroll
        for (int s = 0; s < 4; ++s) {
            short8 B = *(const short8*)&wb2[((size_t)(kt*4 + quad) * 64 + s*16 + l16) * 8];
            acc2[s] = __builtin_amdgcn_mfma_f32_16x16x32_bf16(A, B, acc2[s], 0, 0, 0);
        }
    }
    #pragma unroll
    for (int s = 0; s < 4; ++s)
        #pragma unroll
        for (int r = 0; r < 4; ++r) {
            int nn = n0 + wv*16 + quad*4 + r;
            if (nn < N_NODES)
                esm[(size_t)nn * H2 + s*16 + l16] = fmaxf(acc2[s][r], 0.f);
        }
}

// ---------------------------------------------------------------- last head
__global__ __launch_bounds__(192) void k_last(
    const float* __restrict__ hdec, const float* __restrict__ esm,
    const float* __restrict__ w1, const float* __restrict__ b1,
    const float* __restrict__ w2, const float* __restrict__ b2,
    float* __restrict__ out) {
    __shared__ float s_in[TN][196];
    __shared__ float s_h[TN][196];
    __shared__ float s_w2[192];
    int tid = threadIdx.x;
    int n0  = blockIdx.x * TN;

    s_w2[tid] = w2[tid];
    #pragma unroll 4
    for (int e = 0; e < TN; ++e) {
        int n = n0 + e;
        if (n < N_NODES) {
            s_in[e][tid] = (tid < H1) ? hdec[n * H1 + tid] : esm[n * H2 + (tid - H1)];
        } else {
            s_in[e][tid] = 0.f;
        }
    }
    __syncthreads();

    float acc[TN];
    {
        float bb = b1[tid];
        #pragma unroll
        for (int e = 0; e < TN; ++e) acc[e] = bb;
    }
    for (int k = 0; k < 192; k += 4) {
        float w0  = w1[(k+0)*192 + tid];
        float w1_ = w1[(k+1)*192 + tid];
        float w2_ = w1[(k+2)*192 + tid];
        float w3  = w1[(k+3)*192 + tid];
        #pragma unroll
        for (int e = 0; e < TN; ++e) {
            const float4 x = *(const float4*)&s_in[e][k];
            acc[e] = fmaf(x.x, w0, acc[e]);
            acc[e] = fmaf(x.y, w1_, acc[e]);
            acc[e] = fmaf(x.z, w2_, acc[e]);
            acc[e] = fmaf(x.w, w3, acc[e]);
        }
    }
    #pragma unroll
    for (int e = 0; e < TN; ++e) s_h[e][tid] = silu_f(acc[e]);
    __syncthreads();

    if (tid < TN) {
        int n = n0 + tid;
        if (n < N_NODES) {
            float s = 0.f;
            for (int j = 0; j < 192; ++j) s = fmaf(s_h[tid][j], s_w2[j], s);
            out[n] = sigm_f(s + b2[0]);
        }
    }
}

// ----------------------------------------------------------------
extern "C" void kernel_launch(void* const* d_in, const int* in_sizes, int n_in,
                              void* d_out, int out_size, void* d_ws, size_t ws_size,
                              hipStream_t stream) {
    const float* na      = (const float*)d_in[0];
    const float* coords  = (const float*)d_in[1];
    const int*   ei      = (const int*)  d_in[2];
    const float* ea      = (const float*)d_in[3];
    const float* emb_w   = (const float*)d_in[4];
    const float* emb_b   = (const float*)d_in[5];
    const float* edge_w1 = (const float*)d_in[6];
    const float* edge_b1 = (const float*)d_in[7];
    const float* edge_w2 = (const float*)d_in[8];
    const float* edge_b2 = (const float*)d_in[9];
    const float* att_w   = (const float*)d_in[10];
    const float* att_b   = (const float*)d_in[11];
    const float* node_w1 = (const float*)d_in[12];
    const float* node_b1 = (const float*)d_in[13];
    const float* node_w2 = (const float*)d_in[14];
    const float* node_b2 = (const float*)d_in[15];
    const float* dec_w1  = (const float*)d_in[16];
    const float* dec_b1  = (const float*)d_in[17];
    const float* dec_w2  = (const float*)d_in[18];
    const float* dec_b2  = (const float*)d_in[19];
    const float* ffnn_w1 = (const float*)d_in[20];
    const float* ffnn_b1 = (const float*)d_in[21];
    const float* ffnn_w2 = (const float*)d_in[22];
    const float* ffnn_b2 = (const float*)d_in[23];
    const float* last_w1 = (const float*)d_in[24];
    const float* last_b1 = (const float*)d_in[25];
    const float* last_w2 = (const float*)d_in[26];
    const float* last_b2 = (const float*)d_in[27];

    // workspace: h | agg = exactly 51.2 MB (ws_size is known to be < 54.4 MB — do not grow)
    const size_t need = 2ull * N_NODES * H1 * sizeof(float);
    if (ws_size < need) return;

    float* h    = (float*)d_ws;
    float* agg  = h + (size_t)N_NODES * H1;
    float* hdec = agg;
    float* esm  = h;                       // esm uses h[0 .. 3.2M floats) (12.8 MB)
    float* out  = (float*)d_out;

    // packed bf16 ffnn weights live in the tail of h, which is dead after k_dec:
    //   wb1 at float offset 4,194,304 (16 MB): 163840 floats (655 KB)
    //   wb2 right after: 4096 floats (16 KB). h region is 6.4M floats — no overlap with esm.
    unsigned short* wb1 = (unsigned short*)(h + 4194304);
    unsigned short* wb2 = (unsigned short*)(h + 4194304 + 163840);

    // packed bf16 node weights (per layer) live in d_out, dead until k_last:
    //   wnb1: 44*128*8 shorts = 90112 B, wnb2: 16*128*8 shorts = 32768 B -> 122880 B <= 200000 B
    unsigned short* wnb1 = (unsigned short*)d_out;
    unsigned short* wnb2 = wnb1 + 45056;

    int nblk  = (N_NODES + TN - 1) / TN;
    int nblkF = (N_NODES + TFM - 1) / TFM;   // 782
    int n4    = N_NODES * H1 / 4;

    k_emb<<<N_NODES, H1, 0, stream>>>(na, emb_w, emb_b, h);

    for (int i = 0; i < 4; ++i) {
        k_zero<<<(n4 + 255) / 256, 256, 0, stream>>>((float4*)agg, n4);
        k_edge_mfma<<<GRID_E, 256, 0, stream>>>(
            h, ei, coords, ea,
            edge_w1 + (size_t)i * 258 * H1, edge_b1 + i * H1,
            edge_w2 + (size_t)i * H1 * H1,  edge_b2 + i * H1,
            att_w + i * H1, att_b + i, agg);
        // pack this layer's node weights (tiny; overlaps nothing but ~4 us total)
        k_cvt_pad<<<22, 256, 0, stream>>>(node_w1 + (size_t)i * 339 * H1, wnb1, 339, 44 * H1);
        k_cvt_pad<<<8,  256, 0, stream>>>(node_w2 + (size_t)i * H1 * H1,  wnb2, 128, 16 * H1);
        k_node_mfma<<<nblkF, 256, 0, stream>>>(
            na, agg, wnb1, node_b1 + i * H1, wnb2, node_b2 + i * H1, h);
    }

    k_dec<<<nblk, 128, 0, stream>>>(h, dec_w1, dec_b1, dec_w2, dec_b2, hdec);

    // h is now dead except esm region -> pack ffnn weights into its tail, then MFMA ffnn
    k_cvt_pack<<<160, 256, 0, stream>>>(ffnn_w1, wb1, 160 * 256, 8);   // 1280x256
    k_cvt_pack<<<8,   256, 0, stream>>>(ffnn_w2, wb2, 32 * 64,   6);   // 256x64
    k_ffnn_mfma<<<nblkF, 256, 0, stream>>>(na, wb1, ffnn_b1, wb2, ffnn_b2, esm);

    k_last<<<nblk, 192, 0, stream>>>(hdec, esm, last_w1, last_b1, last_w2, last_b2, out);
}